// Round 7
// baseline (621.518 us; speedup 1.0000x reference)
//
#include <hip/hip_runtime.h>
#include <hip/hip_bf16.h>
#include <stdint.h>

typedef unsigned long long u64;
typedef unsigned short ushort_t;
typedef __attribute__((ext_vector_type(8))) short short8;
typedef __attribute__((ext_vector_type(8))) _Float16 half8;
typedef __attribute__((ext_vector_type(16))) float f32x16;

// Dims: B=512,N=100 -> M=51200; T=100, L=50 conv pos, HE=64, E=128, NE=512, HD=256.

// ---------------- workspace layout (float offsets) ----------------
#define WS_RNP0     0ll          // 51200 f32 (rownorm partial wave0)  -> end    51,200
#define WS_RNP1     51200ll      // 51200 f32 (partial wave1)          -> end   102,400
#define WS_ZHI      102400ll     // 51200*128 ushort = 3,276,800 f     -> end 3,379,200
#define WS_ZLO      3379200ll    // 3,276,800 f                        -> end 6,656,000
#define WS_ENCBHI   6656000ll    // 12288 ushort = 6144 f              -> end 6,662,144
#define WS_ENCBLO   6662144ll    // 6144 f                             -> end 6,668,288
#define WS_CBHI     6668288ll    // 65536 ushort = 32768 f             -> end 6,701,056
#define WS_CBLO     6701056ll    // 32768 f                            -> end 6,733,824
#define WS_CBNORM   6733824ll    // 512 f                              -> end 6,734,336
#define WS_D1F      6734336ll    // 32768 ushort = 16384 f             -> end 6,750,720
#define WS_D2F      6750720ll    // 65536 ushort = 32768 f             -> end 6,783,488
#define WS_D3F      6783488ll    // 32768 ushort = 16384 f             -> end 6,799,872
#define WS_ACCUMS   6799872ll    // 8 f32                              -> end 6,799,880
#define WS_GBEST    6799880ll    // 51200 u64 = 102,400 f (byte%8==0)  -> end 6,902,280
#define WS_H1       6902280ll    // 51200*256 ushort = 6,553,600 f     -> end 13,455,880
#define WS_H2       13455880ll   // 6,553,600 f                        -> end 20,009,480 (~80 MB)

__device__ __host__ inline ushort_t bf16_rn(float v) {
  unsigned u = __float_as_uint(v);
  unsigned r = (u + 0x7fffu + ((u >> 16) & 1u)) >> 16;
  return (ushort_t)r;
}
union h2u { _Float16 h; unsigned short u; };
union s2h { short8 s; half8 h; };

__device__ inline int rowfn(int r, int half) { return (r & 3) + 8*(r >> 2) + 4*half; }

// ---------------- prep: frag-pack all weights + codebook norms ----------------
__global__ __launch_bounds__(256) void prep_kernel(
    const float* __restrict__ w2, const float* __restrict__ cb,
    const float* __restrict__ d1w, const float* __restrict__ d2w,
    const float* __restrict__ d3w,
    ushort_t* __restrict__ ebhi, ushort_t* __restrict__ eblo,
    ushort_t* __restrict__ cbhi, ushort_t* __restrict__ cblo,
    ushort_t* __restrict__ d1f, ushort_t* __restrict__ d2f,
    ushort_t* __restrict__ d3f, float* __restrict__ cbnorm)
{
  const int total = 12288 + 65536 + 32768 + 65536 + 32768 + 512;
  for (int i = blockIdx.x*256 + threadIdx.x; i < total; i += gridDim.x*256) {
    int idx = i;
    if (idx < 12288) {
      // encoder conv2 B-frags (bf16 hi/lo), 32x32x16: f=((t*2+nt)*4+kt)
      int j = idx & 7, l6 = (idx >> 3) & 63, f = idx >> 9;
      int kt = f & 3, ntt = (f >> 2) & 1, t = f >> 3;
      int oc = ntt*32 + (l6 & 31);
      int ic = kt*16 + (l6 >> 5)*8 + j;
      float v = w2[(oc*64 + ic)*3 + t];
      ushort_t hi = bf16_rn(v);
      float hf = __uint_as_float(((unsigned)hi) << 16);
      ebhi[idx] = hi; eblo[idx] = bf16_rn(v - hf); continue;
    }
    idx -= 12288;
    if (idx < 65536) {
      // codebook f16 hi/lo frags, scaled x512: ntg16 x kt8
      int j = idx & 7, l6 = (idx >> 3) & 63, f = idx >> 9;
      int kt = f & 7, ntg = f >> 3;
      int k = kt*16 + (l6 >> 5)*8 + j;
      int n = ntg*32 + (l6 & 31);
      float v = cb[n*128 + k] * 512.0f;
      h2u a, b; a.h = (_Float16)v;
      b.h = (_Float16)(v - (float)a.h);
      cbhi[idx] = a.u; cblo[idx] = b.u; continue;
    }
    idx -= 65536;
    if (idx < 32768) {
      int j = idx & 7, l6 = (idx >> 3) & 63, f = idx >> 9;
      int kt = f & 7, ntg = f >> 3;
      int k = kt*16 + (l6 >> 5)*8 + j;
      int n = ntg*32 + (l6 & 31);
      d1f[idx] = bf16_rn(d1w[n*128 + k]); continue;
    }
    idx -= 32768;
    if (idx < 65536) {
      int j = idx & 7, l6 = (idx >> 3) & 63, f = idx >> 9;
      int kt = f & 15, ntg = f >> 4;
      int k = kt*16 + (l6 >> 5)*8 + j;
      int n = ntg*32 + (l6 & 31);
      d2f[idx] = bf16_rn(d2w[n*256 + k]); continue;
    }
    idx -= 65536;
    if (idx < 32768) {
      int j = idx & 7, l6 = (idx >> 3) & 63, f = idx >> 9;
      int kt = f & 15, ntg = f >> 4;
      int k = kt*16 + (l6 >> 5)*8 + j;
      int n = ntg*32 + (l6 & 31);
      d3f[idx] = (n < 100) ? bf16_rn(d3w[n*256 + k]) : (ushort_t)0; continue;
    }
    idx -= 32768;
    { double s = 0.0; const float* c = cb + idx*128;
      for (int e = 0; e < 128; ++e) { double v = (double)c[e]; s += v*v; }
      cbnorm[idx] = (float)s; }
  }
}

// ---------------- encoder: R6 skeleton + packed bf16 split + t0 prefetch ----------------
// w1,b1,b2,latw,latb NOT __restrict: keep loads in-loop (wave-uniform s_loads / L1).
__global__ __launch_bounds__(256) void encoder_kernel(
    const float* __restrict__ x, const float* __restrict__ tm,
    const float* __restrict__ imask,
    const float* w1, const float* b1,
    const ushort_t* __restrict__ ebhi, const ushort_t* __restrict__ eblo,
    const float* b2, const float* latw, const float* latb,
    ushort_t* zhi, ushort_t* zlo, float* rnp0, float* rnp1)
{
  __shared__ float s_h0[104];         // 2 channels, halo'd length 52
  __shared__ ushort_t s_Hhi[52*72];   // conv1 out bf16-hi: row = pos+1 (rows 0,51 zero)
  __shared__ ushort_t s_Hlo[52*72];
  __shared__ float s_red[2][64];
  const int m = blockIdx.x;
  const int tid = threadIdx.x;
  const int wv   = __builtin_amdgcn_readfirstlane((int)(tid >> 6));
  const int lane = tid & 63;
  const int ln31 = lane & 31, half = lane >> 5;
  const int mt = wv >> 1, nt = wv & 1;
  const int o0 = wv*16;
  const float imv = imask[m];   // uniform -> scalar load

  // prefetch t=0 Bh frags (16 VGPR) — hides first vmcnt stall in MFMA loop
  short8 Bh0[4];
  {
    const short8* bh8 = (const short8*)ebhi;
    #pragma unroll
    for (int kt = 0; kt < 4; ++kt)
      Bh0[kt] = bh8[(nt*4 + kt)*64 + lane];   // f = ((0*2+nt)*4+kt)
  }

  // one-time LDS zero init (visible after SYNC_B / SYNC_C)
  if (tid < 2)  { s_h0[tid*52] = 0.f; s_h0[tid*52 + 51] = 0.f; }
  if (tid < 36) { ((unsigned*)s_Hhi)[tid] = 0u; ((unsigned*)s_Hlo)[tid] = 0u; }  // H row 0

  // ---- x/tm staged via LDS (keeps VGPR low; 100 threads, 2 loads each) ----
  if (tid < 100) {
    // channel c = tid&1, pos l = tid>>1
    s_h0[(tid & 1)*52 + 1 + (tid >> 1)] =
        x[(long)m*100 + tid] * tm[(long)m*100 + tid] * imv;
  }
  __syncthreads();   // SYNC_B: s_h0 ready

  // ---- conv1 (f32) + packed bf16 hi/lo split (v_cvt_pk_bf16_f32 path) ----
  {
    const int ll = (lane < 50) ? lane : 0;
    const float a0 = s_h0[ll],    a1 = s_h0[ll+1],    a2 = s_h0[ll+2];
    const float c0 = s_h0[52+ll], c1 = s_h0[52+ll+1], c2 = s_h0[52+ll+2];
    unsigned hiu[8], lou[8];
    #pragma unroll
    for (int p = 0; p < 8; ++p) {
      float hv[2];
      #pragma unroll
      for (int q = 0; q < 2; ++q) {
        const int o = o0 + p*2 + q;
        const float* w = w1 + o*6;        // wave-uniform -> s_load
        float h = b1[o];
        h = fmaf(w[0], a0, h); h = fmaf(w[1], a1, h); h = fmaf(w[2], a2, h);
        h = fmaf(w[3], c0, h); h = fmaf(w[4], c1, h); h = fmaf(w[5], c2, h);
        h = fmaxf(h, 0.f);
        if (lane >= 50) h = 0.f;
        hv[q] = h;
      }
      float2 hp; hp.x = hv[0]; hp.y = hv[1];
      union { __hip_bfloat162 b; unsigned u; } cv;
      cv.b = __float22bfloat162_rn(hp);           // RNE pair (== bf16_rn x2)
      hiu[p] = cv.u;
      const float hf0 = __uint_as_float(cv.u << 16);
      const float hf1 = __uint_as_float(cv.u & 0xffff0000u);
      float2 lp; lp.x = hv[0] - hf0; lp.y = hv[1] - hf1;
      union { __hip_bfloat162 b; unsigned u; } cl;
      cl.b = __float22bfloat162_rn(lp);
      lou[p] = cl.u;
    }
    if (lane < 51) {
      short8* dh = (short8*)(s_Hhi + (lane+1)*72 + o0);
      short8* dl = (short8*)(s_Hlo + (lane+1)*72 + o0);
      dh[0] = *(short8*)&hiu[0]; dh[1] = *(short8*)&hiu[4];
      dl[0] = *(short8*)&lou[0]; dl[1] = *(short8*)&lou[4];
    }
  }
  __syncthreads();   // SYNC_C: H ready

  // ---- conv2 MFMA: 3 taps x 4 k-tiles x 3 passes (t0 Bh prefetched, rest JIT) ----
  f32x16 acc;
  #pragma unroll
  for (int q = 0; q < 16; ++q) acc[q] = 0.f;
  {
    const short8* bh8 = (const short8*)ebhi;
    const short8* bl8 = (const short8*)eblo;
    #pragma unroll
    for (int t = 0; t < 3; ++t) {
      int rowA = mt*32 + ln31 + t;
      if (rowA > 51) rowA = 51;
      const int base8 = rowA*9 + half;   // short8 index (72/8 = 9)
      #pragma unroll
      for (int kt = 0; kt < 4; ++kt) {
        const int f = ((t*2 + nt)*4 + kt);
        const short8 Bh = (t == 0) ? Bh0[kt] : bh8[f*64 + lane];
        const short8 Bl = bl8[f*64 + lane];
        const short8 ah = ((const short8*)s_Hhi)[base8 + kt*2];
        const short8 al = ((const short8*)s_Hlo)[base8 + kt*2];
        acc = __builtin_amdgcn_mfma_f32_32x32x16_bf16(ah, Bh, acc, 0, 0, 0);
        acc = __builtin_amdgcn_mfma_f32_32x32x16_bf16(ah, Bl, acc, 0, 0, 0);
        acc = __builtin_amdgcn_mfma_f32_32x32x16_bf16(al, Bh, acc, 0, 0, 0);
      }
    }
  }
  // relu + sum over pos<50 (mt==0 rows all <50 -> unconditional)
  {
    const float bias2 = b2[nt*32 + ln31];
    float sum = 0.f;
    if (mt == 0) {
      #pragma unroll
      for (int r = 0; r < 16; ++r) sum += fmaxf(acc[r] + bias2, 0.f);
    } else {
      #pragma unroll
      for (int r = 0; r < 16; ++r) {
        const int mpos = 32 + rowfn(r, half);
        const float v = fmaxf(acc[r] + bias2, 0.f);
        if (mpos < 50) sum += v;
      }
    }
    sum += __shfl_xor(sum, 32);
    if (half == 0) s_red[mt][nt*32 + ln31] = sum;
  }
  __syncthreads();   // SYNC_D: s_red ready

  // ---- latent (f32): z[e] = (lat_b + 0.02*sum_ic (red0+red1)[ic]*latw[e][ic]) * imv ----
  if (tid < 128) {
    float a = 0.f;
    const float4* r0 = (const float4*)s_red[0];
    const float4* r1 = (const float4*)s_red[1];
    const float4* wp = (const float4*)(latw + tid*64);
    #pragma unroll
    for (int q = 0; q < 16; ++q) {
      const float4 w4 = wp[q];
      const float4 a4 = r0[q]; const float4 b4 = r1[q];
      a = fmaf(w4.x, a4.x + b4.x, a);
      a = fmaf(w4.y, a4.y + b4.y, a);
      a = fmaf(w4.z, a4.z + b4.z, a);
      a = fmaf(w4.w, a4.w + b4.w, a);
    }
    const float z = fmaf(0.02f, a, latb[tid]) * imv;
    h2u zh; zh.h = (_Float16)z;
    h2u zl; zl.h = (_Float16)(z - (float)zh.h);
    zhi[(long)m*128 + tid] = zh.u;
    zlo[(long)m*128 + tid] = zl.u;
    // rownorm partial per wave (wave0: e=0..63, wave1: e=64..127), no extra barrier
    float v = z*z;
    #pragma unroll
    for (int off = 32; off > 0; off >>= 1) v += __shfl_down(v, off);
    if (lane == 0) { if (wv == 0) rnp0[m] = v; else rnp1[m] = v; }
  }
}

// ---------------- VQ: f16 3-pass MFMA, 32 rows x all 512 codes per block ----------------
__global__ __launch_bounds__(256) void vq_kernel(
    const ushort_t* __restrict__ zhi, const ushort_t* __restrict__ zlo,
    const ushort_t* __restrict__ cbhi, const ushort_t* __restrict__ cblo,
    const float* __restrict__ rnp0, const float* __restrict__ rnp1,
    const float* __restrict__ cbnorm, u64* __restrict__ gbest)
{
  __shared__ ushort_t s_ah[32*136];
  __shared__ ushort_t s_al[32*136];
  __shared__ float s_rn[32];
  __shared__ u64 s_best[32];
  const int tid = threadIdx.x;
  const int m0 = blockIdx.x * 32;
  {
    const short8* gh = (const short8*)(zhi + (long)m0*128);
    const short8* gl = (const short8*)(zlo + (long)m0*128);
    const int row = tid >> 3, c8 = (tid & 7)*2;
    ((short8*)s_ah)[row*17 + c8]     = gh[tid*2];
    ((short8*)s_ah)[row*17 + c8 + 1] = gh[tid*2 + 1];
    ((short8*)s_al)[row*17 + c8]     = gl[tid*2];
    ((short8*)s_al)[row*17 + c8 + 1] = gl[tid*2 + 1];
  }
  if (tid < 32) { s_rn[tid] = rnp0[m0 + tid] + rnp1[m0 + tid]; s_best[tid] = ~0ULL; }
  __syncthreads();

  const int wv = tid >> 6, lane = tid & 63;
  const int ln31 = lane & 31, half = lane >> 5;
  float rnv[16];
  #pragma unroll
  for (int r = 0; r < 16; ++r) rnv[r] = s_rn[rowfn(r, half)];

  u64 best[16];
  #pragma unroll
  for (int r = 0; r < 16; ++r) best[r] = ~0ULL;

  const short8* ch8 = (const short8*)cbhi;
  const short8* cl8 = (const short8*)cblo;
  for (int ct = 0; ct < 4; ++ct) {
    const int ntg = wv*4 + ct;
    half8 Bh[8], Bl[8];
    #pragma unroll
    for (int kt = 0; kt < 8; ++kt) {
      s2h a, b;
      a.s = ch8[(ntg*8 + kt)*64 + lane];
      b.s = cl8[(ntg*8 + kt)*64 + lane];
      Bh[kt] = a.h; Bl[kt] = b.h;
    }
    f32x16 acc;
    #pragma unroll
    for (int q = 0; q < 16; ++q) acc[q] = 0.f;
    const int base8 = ln31*17 + half;
    #pragma unroll
    for (int kt = 0; kt < 8; ++kt) {
      s2h ah, al;
      ah.s = ((const short8*)s_ah)[base8 + kt*2];
      al.s = ((const short8*)s_al)[base8 + kt*2];
      acc = __builtin_amdgcn_mfma_f32_32x32x16_f16(ah.h, Bh[kt], acc, 0, 0, 0);
      acc = __builtin_amdgcn_mfma_f32_32x32x16_f16(ah.h, Bl[kt], acc, 0, 0, 0);
      acc = __builtin_amdgcn_mfma_f32_32x32x16_f16(al.h, Bh[kt], acc, 0, 0, 0);
    }
    const int code = ntg*32 + ln31;
    const float nrm = cbnorm[code];
    #pragma unroll
    for (int r = 0; r < 16; ++r) {
      const float t = fmaf(-0.00390625f, acc[r], rnv[r]);  // A - p/256 (cb scaled x512)
      const float d = t + nrm;
      const u64 pk = ((u64)__float_as_uint(d) << 32) | (u64)(unsigned)code;
      if (pk < best[r]) best[r] = pk;
    }
  }
  #pragma unroll
  for (int r = 0; r < 16; ++r) atomicMin(&s_best[rowfn(r, half)], best[r]);
  __syncthreads();
  if (tid < 32) gbest[m0 + tid] = s_best[tid];
}

// ---------------- decoder GEMM 1 + fused indices/vq-loss/S_im ----------------
__global__ __launch_bounds__(256) void dec1_kernel(
    const float* __restrict__ cb, const u64* __restrict__ gbest,
    const float* __restrict__ imask, const ushort_t* __restrict__ bfrag,
    const float* __restrict__ bias, ushort_t* __restrict__ h1out,
    float* __restrict__ out_idx, float* __restrict__ accums)
{
  __shared__ ushort_t s_a[64*136];
  __shared__ int s_idx[64];
  __shared__ float s_act[64];
  const int tid = threadIdx.x;
  const long m0 = (long)blockIdx.x * 64;
  if (tid < 64) {
    const u64 pk = gbest[m0 + tid];
    const int ii = (int)(unsigned)(pk & 0xffffffffULL);
    const float dd = __uint_as_float((unsigned)(pk >> 32));
    const float imv = imask[m0 + tid];
    s_idx[tid] = ii; s_act[tid] = imv;
    out_idx[m0 + tid] = (imv > 0.f) ? (float)ii : -1.0f;
    float vqp = 1.25f * dd * (1.0f/128.0f) * imv;
    float sim = imv;
    #pragma unroll
    for (int off = 32; off > 0; off >>= 1) {
      vqp += __shfl_down(vqp, off); sim += __shfl_down(sim, off);
    }
    if (tid == 0) { atomicAdd(&accums[1], vqp); atomicAdd(&accums[3], sim); }
  }
  __syncthreads();
  {
    const int row = tid >> 2, seg = tid & 3;
    const float4* src = (const float4*)(cb + (long)s_idx[row]*128 + seg*32);
    const float im = s_act[row];
    ushort_t tmp[32];
    #pragma unroll
    for (int q = 0; q < 8; ++q) {
      const float4 v = src[q];
      tmp[q*4+0] = bf16_rn(v.x*im); tmp[q*4+1] = bf16_rn(v.y*im);
      tmp[q*4+2] = bf16_rn(v.z*im); tmp[q*4+3] = bf16_rn(v.w*im);
    }
    short8* dst = (short8*)(s_a + row*136 + seg*32);
    #pragma unroll
    for (int q = 0; q < 4; ++q) dst[q] = *(short8*)&tmp[q*8];
  }
  __syncthreads();
  const int wv = tid >> 6, lane = tid & 63;
  const int ln31 = lane & 31, half = lane >> 5;
  const short8* bf = (const short8*)bfrag;
  #pragma unroll
  for (int nti = 0; nti < 2; ++nti) {
    const int ntg = wv + nti*4;
    short8 B[8];
    #pragma unroll
    for (int kt = 0; kt < 8; ++kt) B[kt] = bf[(ntg*8 + kt)*64 + lane];
    const float bv = bias[ntg*32 + ln31];
    #pragma unroll
    for (int mtl = 0; mtl < 2; ++mtl) {
      f32x16 acc;
      #pragma unroll
      for (int q = 0; q < 16; ++q) acc[q] = 0.f;
      const int base8 = (mtl*32 + ln31)*17 + half;
      #pragma unroll
      for (int kt = 0; kt < 8; ++kt) {
        const short8 a = ((const short8*)s_a)[base8 + kt*2];
        acc = __builtin_amdgcn_mfma_f32_32x32x16_bf16(a, B[kt], acc, 0, 0, 0);
      }
      const int col = ntg*32 + ln31;
      #pragma unroll
      for (int r = 0; r < 16; ++r) {
        const long row = m0 + mtl*32 + rowfn(r, half);
        h1out[row*256 + col] = bf16_rn(fmaxf(acc[r] + bv, 0.f));
      }
    }
  }
}

// ---------------- decoder GEMM 2: h2 = relu(h1 @ d2^T + b), K=256 ----------------
__global__ __launch_bounds__(256) void dec2_kernel(
    const ushort_t* __restrict__ ain, const ushort_t* __restrict__ bfrag,
    const float* __restrict__ bias, ushort_t* __restrict__ outbuf)
{
  __shared__ ushort_t s_a[64*264];
  const int tid = threadIdx.x;
  const long m0 = (long)blockIdx.x * 64;
  {
    const int row = tid >> 2, seg = tid & 3;
    const short8* src = (const short8*)(ain + (m0 + row)*256 + seg*64);
    short8* dst = (short8*)(s_a + row*264 + seg*64);
    #pragma unroll
    for (int q = 0; q < 8; ++q) dst[q] = src[q];
  }
  __syncthreads();
  const int wv = tid >> 6, lane = tid & 63;
  const int ln31 = lane & 31, half = lane >> 5;
  const short8* bf = (const short8*)bfrag;
  #pragma unroll
  for (int nti = 0; nti < 2; ++nti) {
    const int ntg = wv + nti*4;
    short8 B[16];
    #pragma unroll
    for (int kt = 0; kt < 16; ++kt) B[kt] = bf[(ntg*16 + kt)*64 + lane];
    const float bv = bias[ntg*32 + ln31];
    #pragma unroll
    for (int mtl = 0; mtl < 2; ++mtl) {
      f32x16 acc;
      #pragma unroll
      for (int q = 0; q < 16; ++q) acc[q] = 0.f;
      const int base8 = (mtl*32 + ln31)*33 + half;
      #pragma unroll
      for (int kt = 0; kt < 16; ++kt) {
        const short8 a = ((const short8*)s_a)[base8 + kt*2];
        acc = __builtin_amdgcn_mfma_f32_32x32x16_bf16(a, B[kt], acc, 0, 0, 0);
      }
      const int col = ntg*32 + ln31;
      #pragma unroll
      for (int r = 0; r < 16; ++r) {
        const long row = m0 + mtl*32 + rowfn(r, half);
        outbuf[row*256 + col] = bf16_rn(fmaxf(acc[r] + bv, 0.f));
      }
    }
  }
}

// ---------------- decoder GEMM 3: x_hat + recon loss + S_rw ----------------
__global__ __launch_bounds__(256) void dec3_kernel(
    const ushort_t* __restrict__ ain, const ushort_t* __restrict__ bfrag,
    const float* __restrict__ bias, const float* __restrict__ x,
    const float* __restrict__ tm, const float* __restrict__ imask,
    float* __restrict__ xhat, float* __restrict__ accums)
{
  __shared__ ushort_t s_a[64*264];
  const int tid = threadIdx.x;
  const long m0 = (long)blockIdx.x * 64;
  {
    const int row = tid >> 2, seg = tid & 3;
    const short8* src = (const short8*)(ain + (m0 + row)*256 + seg*64);
    short8* dst = (short8*)(s_a + row*264 + seg*64);
    #pragma unroll
    for (int q = 0; q < 8; ++q) dst[q] = src[q];
  }
  __syncthreads();
  const int wv = tid >> 6, lane = tid & 63;
  const int ln31 = lane & 31, half = lane >> 5;
  const short8* bf = (const short8*)bfrag;
  const int ntg = wv;
  short8 B[16];
  #pragma unroll
  for (int kt = 0; kt < 16; ++kt) B[kt] = bf[(ntg*16 + kt)*64 + lane];
  const int col = ntg*32 + ln31;
  const float bv = (col < 100) ? bias[col] : 0.f;
  float part = 0.f, wsum = 0.f;
  #pragma unroll
  for (int mtl = 0; mtl < 2; ++mtl) {
    f32x16 acc;
    #pragma unroll
    for (int q = 0; q < 16; ++q) acc[q] = 0.f;
    const int base8 = (mtl*32 + ln31)*33 + half;
    #pragma unroll
    for (int kt = 0; kt < 16; ++kt) {
      const short8 a = ((const short8*)s_a)[base8 + kt*2];
      acc = __builtin_amdgcn_mfma_f32_32x32x16_bf16(a, B[kt], acc, 0, 0, 0);
    }
    if (col < 100) {
      #pragma unroll
      for (int r = 0; r < 16; ++r) {
        const long row = m0 + mtl*32 + rowfn(r, half);
        const float xh = acc[r] + bv;
        xhat[row*100 + col] = xh;
        const float wgt = imask[row] * tm[row*100 + col];
        const float df = xh - x[row*100 + col];
        part = fmaf(df*df, wgt, part);
        wsum += wgt;
      }
    }
  }
  #pragma unroll
  for (int off = 32; off > 0; off >>= 1) {
    part += __shfl_down(part, off); wsum += __shfl_down(wsum, off);
  }
  __shared__ float s_p[4], s_w[4];
  if (lane == 0) { s_p[wv] = part; s_w[wv] = wsum; }
  __syncthreads();
  if (tid == 0) {
    atomicAdd(&accums[0], s_p[0]+s_p[1]+s_p[2]+s_p[3]);
    atomicAdd(&accums[2], s_w[0]+s_w[1]+s_w[2]+s_w[3]);
  }
}

// ---------------- finalize scalars ----------------
__global__ void finalize_kernel(const float* __restrict__ accums, float* __restrict__ out) {
  if (threadIdx.x == 0 && blockIdx.x == 0) {
    out[5120000] = accums[0] / fmaxf(accums[2], 1.0f);
    out[5120001] = accums[1] / fmaxf(accums[3], 1.0f);
  }
}

extern "C" void kernel_launch(void* const* d_in, const int* in_sizes, int n_in,
                              void* d_out, int out_size, void* d_ws, size_t ws_size,
                              hipStream_t stream)
{
  (void)in_sizes; (void)n_in; (void)out_size; (void)ws_size;
  const float* x     = (const float*)d_in[0];
  const float* tmsk  = (const float*)d_in[1];
  const float* imask = (const float*)d_in[2];
  const float* w1    = (const float*)d_in[3];
  const float* b1    = (const float*)d_in[4];
  const float* w2    = (const float*)d_in[5];
  const float* b2    = (const float*)d_in[6];
  const float* latw  = (const float*)d_in[7];
  const float* latb  = (const float*)d_in[8];
  const float* cb    = (const float*)d_in[9];
  const float* d1w   = (const float*)d_in[10];
  const float* d1b   = (const float*)d_in[11];
  const float* d2w   = (const float*)d_in[12];
  const float* d2b   = (const float*)d_in[13];
  const float* d3w   = (const float*)d_in[14];
  const float* d3b   = (const float*)d_in[15];
  float* out = (float*)d_out;
  float* ws  = (float*)d_ws;

  float*    rnp0   = ws + WS_RNP0;
  float*    rnp1   = ws + WS_RNP1;
  ushort_t* zhi    = (ushort_t*)(ws + WS_ZHI);
  ushort_t* zlo    = (ushort_t*)(ws + WS_ZLO);
  ushort_t* ebhi   = (ushort_t*)(ws + WS_ENCBHI);
  ushort_t* eblo   = (ushort_t*)(ws + WS_ENCBLO);
  ushort_t* cbhi   = (ushort_t*)(ws + WS_CBHI);
  ushort_t* cblo   = (ushort_t*)(ws + WS_CBLO);
  float*    cbnorm = ws + WS_CBNORM;
  ushort_t* d1f    = (ushort_t*)(ws + WS_D1F);
  ushort_t* d2f    = (ushort_t*)(ws + WS_D2F);
  ushort_t* d3f    = (ushort_t*)(ws + WS_D3F);
  float*    accums = ws + WS_ACCUMS;
  u64*      gbest  = (u64*)(ws + WS_GBEST);
  ushort_t* h1     = (ushort_t*)(ws + WS_H1);
  ushort_t* h2     = (ushort_t*)(ws + WS_H2);
  float* xhat    = out;
  float* out_idx = out + 5120002;

  hipMemsetAsync(accums, 0, 8*sizeof(float), stream);

  prep_kernel<<<512, 256, 0, stream>>>(w2, cb, d1w, d2w, d3w,
                                       ebhi, eblo, cbhi, cblo, d1f, d2f, d3f, cbnorm);
  encoder_kernel<<<51200, 256, 0, stream>>>(x, tmsk, imask, w1, b1, ebhi, eblo, b2,
                                            latw, latb, zhi, zlo, rnp0, rnp1);
  vq_kernel<<<1600, 256, 0, stream>>>(zhi, zlo, cbhi, cblo, rnp0, rnp1, cbnorm, gbest);
  dec1_kernel<<<800, 256, 0, stream>>>(cb, gbest, imask, d1f, d1b, h1, out_idx, accums);
  dec2_kernel<<<800, 256, 0, stream>>>(h1, d2f, d2b, h2);
  dec3_kernel<<<800, 256, 0, stream>>>(h2, d3f, d3b, x, tmsk, imask, xhat, accums);
  finalize_kernel<<<1, 64, 0, stream>>>(accums, out);
}